// Round 5
// baseline (153923.584 us; speedup 1.0000x reference)
//
#include <hip/hip_runtime.h>
#include <hip/hip_cooperative_groups.h>

namespace cg = cooperative_groups;

#define Bb   256   // batch
#define Tt   512   // time steps
#define INx  19    // input features
#define Hh   512   // hidden
#define NWG  256   // workgroups: (unit-group 0..127) x (batch-half 0..1)
#define NTHR 512   // threads: (uu 0..3) x (ks 0..1) x (bl 0..63)

#define WLDS_FLOATS (48 * Hh)                 // 4 units x 12 rows x 512
#define PART_FLOATS (8192)                    // [16 rowsets][... conflict-free r-major]
#define WX1_FLOATS  (320)                     // 4 units x 4 gates x 20 (pad)
#define SMEM_FLOATS (WLDS_FLOATS + PART_FLOATS + WX1_FLOATS)
#define SMEM_BYTES  (SMEM_FLOATS * 4)

typedef unsigned int u32;

__device__ __forceinline__ float sigf(float x) { return 1.0f / (1.0f + __expf(-x)); }
__device__ __forceinline__ float tanhfast(float x) {
    float e = __expf(2.0f * x);
    return 1.0f - 2.0f / (e + 1.0f);
}
// h stores bypass L1/L2 -> LLC; reads stay cacheable (refreshed by acquire fence in gbar)
__device__ __forceinline__ void gstore(float* p, float v) {
    __hip_atomic_store(p, v, __ATOMIC_RELAXED, __HIP_MEMORY_SCOPE_AGENT);
}

__device__ __forceinline__ void gbar(u32* flags, int wgid, int tid, u32 phase) {
    __syncthreads();   // all waves drain vmem stores before barrier exit
    if (tid == 0)
        __hip_atomic_store(&flags[wgid], phase, __ATOMIC_RELEASE, __HIP_MEMORY_SCOPE_AGENT);
    if (tid < NWG) {
        const u32* fp = &flags[tid];
        while (__hip_atomic_load(fp, __ATOMIC_RELAXED, __HIP_MEMORY_SCOPE_AGENT) < phase)
            __builtin_amdgcn_s_sleep(2);
    }
    __syncthreads();
    __builtin_amdgcn_fence(__ATOMIC_ACQUIRE, "agent");   // L1/L2 refetch of h
}

// load 8 consecutive k's for 2 batches (lane batch b and b+64)
__device__ __forceinline__ void ld8(const float* __restrict__ s, int kb,
                                    float (&P0)[8], float (&P1)[8]) {
    #pragma unroll
    for (int u = 0; u < 8; ++u) {
        P0[u] = s[(kb + u) * Bb];
        P1[u] = s[(kb + u) * Bb + 64];
    }
}

// 8-k block vs rows 0-7 (l1_Wh gates 0-3 -> a1, l2_Wx gates 0-3 -> a2), 2 batches
__device__ __forceinline__ void fm1(const float* __restrict__ wk,
                                    const float (&P0)[8], const float (&P1)[8],
                                    float (&a10)[4], float (&a11)[4],
                                    float (&a20)[4], float (&a21)[4]) {
    #pragma unroll
    for (int q = 0; q < 2; ++q) {
        #pragma unroll
        for (int g = 0; g < 4; ++g) {
            const float4 w1 = *reinterpret_cast<const float4*>(&wk[g * Hh + q * 4]);
            a10[g] += P0[q*4+0]*w1.x + P0[q*4+1]*w1.y + P0[q*4+2]*w1.z + P0[q*4+3]*w1.w;
            a11[g] += P1[q*4+0]*w1.x + P1[q*4+1]*w1.y + P1[q*4+2]*w1.z + P1[q*4+3]*w1.w;
            const float4 w2 = *reinterpret_cast<const float4*>(&wk[(4 + g) * Hh + q * 4]);
            a20[g] += P0[q*4+0]*w2.x + P0[q*4+1]*w2.y + P0[q*4+2]*w2.z + P0[q*4+3]*w2.w;
            a21[g] += P1[q*4+0]*w2.x + P1[q*4+1]*w2.y + P1[q*4+2]*w2.z + P1[q*4+3]*w2.w;
        }
    }
}
// 8-k block vs rows 8-11 (l2_Wh gates 0-3 -> a2), 2 batches
__device__ __forceinline__ void fm2(const float* __restrict__ wk,
                                    const float (&Q0)[8], const float (&Q1)[8],
                                    float (&a20)[4], float (&a21)[4]) {
    #pragma unroll
    for (int q = 0; q < 2; ++q) {
        #pragma unroll
        for (int g = 0; g < 4; ++g) {
            const float4 w3 = *reinterpret_cast<const float4*>(&wk[(8 + g) * Hh + q * 4]);
            a20[g] += Q0[q*4+0]*w3.x + Q0[q*4+1]*w3.y + Q0[q*4+2]*w3.z + Q0[q*4+3]*w3.w;
            a21[g] += Q1[q*4+0]*w3.x + Q1[q*4+1]*w3.y + Q1[q*4+2]*w3.z + Q1[q*4+3]*w3.w;
        }
    }
}

__global__ void __launch_bounds__(NTHR, 2)
lstm_fused(const float* __restrict__ input,
           const float* __restrict__ l1_Wx, const float* __restrict__ l1_bx,
           const float* __restrict__ l1_Wh, const float* __restrict__ l1_bh,
           const float* __restrict__ l2_Wx, const float* __restrict__ l2_bx,
           const float* __restrict__ l2_Wh, const float* __restrict__ l2_bh,
           const float* __restrict__ fc1_W, const float* __restrict__ fc1_b,
           const float* __restrict__ fc2_W, const float* __restrict__ fc2_b,
           const float* __restrict__ fc3_W, const float* __restrict__ fc3_b,
           float* __restrict__ out, float* __restrict__ ws)
{
    extern __shared__ float smem[];
    float* wlds = smem;                    // [4 units][12 rows][512]
    float* part = smem + WLDS_FLOATS;      // [16 rowsets][... x128], r-major
    float* wx1l = part + PART_FLOATS;      // [4 units][4 gates][20]

    cg::grid_group grid = cg::this_grid();
    const int wgid = blockIdx.x;
    const int ug = wgid >> 1;              // unit-group 0..127
    const int bs = wgid & 1;               // batch-half
    const int jb = ug * 4;                 // first owned unit
    const int tid = threadIdx.x;
    const int uu = tid >> 7;               // sweep unit 0..3
    const int ks = (tid >> 6) & 1;         // K-half
    const int bl = tid & 63;               // sweep lane batch
    const int fu = uu;                     // finish unit (same bits)
    const int fb = tid & 127;              // finish local batch
    const int bx = bs * 128 + fb;          // finish global batch

    float* h1A = ws;
    float* h1B = h1A + Hh * Bb;
    float* h2A = h1B + Hh * Bb;
    float* h2B = h2A + Hh * Bb;
    u32*   flags = (u32*)(h2B + Hh * Bb);

    // ---- stage weights into LDS (once; immune to L2 invalidation) ----
    for (int idx = tid; idx < WLDS_FLOATS; idx += NTHR) {
        const int u2 = idx / (12 * Hh);
        const int rem = idx - u2 * (12 * Hh);
        const int r = rem >> 9, k = rem & 511;
        const int m = r >> 2, g = r & 3;
        const float* src = (m == 0) ? l1_Wh : (m == 1) ? l2_Wx : l2_Wh;
        wlds[idx] = src[(size_t)(g * Hh + jb + u2) * Hh + k];
    }
    if (tid < 4 * 4 * INx) {
        const int u2 = tid / (4 * INx), rem = tid - u2 * (4 * INx);
        const int g = rem / INx, i = rem - g * INx;
        wx1l[(u2 * 4 + g) * 20 + i] = l1_Wx[(size_t)(g * Hh + jb + u2) * INx + i];
    }
    float b1r[4], b2r[4];
    #pragma unroll
    for (int g = 0; g < 4; ++g) {
        const int row = g * Hh + jb + fu;
        b1r[g] = l1_bx[row] + l1_bh[row];
        b2r[g] = l2_bx[row] + l2_bh[row];
    }

    // ---- init: h2[-1] = 0, flag reset; fenced by grid.sync ----
    gstore(&h2A[(jb + fu) * Bb + bx], 0.0f);
    if (tid == 0)
        __hip_atomic_store(&flags[wgid], 0u, __ATOMIC_RELAXED, __HIP_MEMORY_SCOPE_AGENT);
    __syncthreads();
    grid.sync();   // the only runtime cg sync

    // ---- prologue: h1[0] = gates(bias1 + x[0]·Wx1), h=0 ----
    float c1, c2 = 0.0f;
    {
        const float* xr = input + (size_t)bx * Tt * INx;
        float g4[4];
        #pragma unroll
        for (int g = 0; g < 4; ++g) {
            float acc = b1r[g];
            #pragma unroll
            for (int i = 0; i < INx; ++i) acc += xr[i] * wx1l[(fu * 4 + g) * 20 + i];
            g4[g] = acc;
        }
        c1 = sigf(g4[0]) * tanhfast(g4[2]);        // f*0 + i*g
        gstore(&h1A[(jb + fu) * Bb + bx], sigf(g4[3]) * tanhfast(c1));
    }
    gbar(flags, wgid, tid, 1u);

    const float* h1c = h1A; float* h1n = h1B;
    const float* h2c = h2A; float* h2n = h2B;

    const int k0 = ks << 8;
    const int bcol = bs * 128 + bl;
    const float* wb = wlds + uu * (12 * Hh);
    const int pb0 = fu * 8;          // partial rowset base, ks=0
    const int pb1 = (4 + fu) * 8;    // partial rowset base, ks=1
    const int pw = (ks * 4 + uu) * 8;

    for (int t = 0; t < Tt; ++t) {
        const bool doL1 = (t < Tt - 1);
        float xv[INx];
        if (doL1) {   // prefetch x[t+1] early; consumed in finish
            const float* xr = input + ((size_t)bx * Tt + t + 1) * INx;
            #pragma unroll
            for (int i = 0; i < INx; ++i) xv[i] = xr[i];
        }

        const float* s1 = h1c + k0 * Bb + bcol;
        const float* s2 = h2c + k0 * Bb + bcol;

        float a10[4] = {0.f,0.f,0.f,0.f}, a11[4] = {0.f,0.f,0.f,0.f};
        float a20[4] = {0.f,0.f,0.f,0.f}, a21[4] = {0.f,0.f,0.f,0.f};

        // dual-stream, double-buffered pipeline over 32 chunks of 8 k's each
        float pA0[8], pA1[8], pB0[8], pB1[8];
        float qA0[8], qA1[8], qB0[8], qB1[8];
        ld8(s1, 0, pA0, pA1);
        ld8(s2, 0, qA0, qA1);
        ld8(s1, 8, pB0, pB1);
        ld8(s2, 8, qB0, qB1);

        for (int c = 0; c < 32; c += 2) {
            const float* wk = wb + k0 + (c << 3);
            fm1(wk, pA0, pA1, a10, a11, a20, a21);
            if (c + 2 < 32) ld8(s1, (c + 2) << 3, pA0, pA1);
            fm2(wk, qA0, qA1, a20, a21);
            if (c + 2 < 32) ld8(s2, (c + 2) << 3, qA0, qA1);
            fm1(wk + 8, pB0, pB1, a10, a11, a20, a21);
            if (c + 3 < 32) ld8(s1, (c + 3) << 3, pB0, pB1);
            fm2(wk + 8, qB0, qB1, a20, a21);
            if (c + 3 < 32) ld8(s2, (c + 3) << 3, qB0, qB1);
        }

        // ---- exchange K-half partials (r-major, b32, 2-way = conflict-free) ----
        #pragma unroll
        for (int g = 0; g < 4; ++g) {
            part[(pw + g) * 128 + bl]          = a10[g];
            part[(pw + g) * 128 + bl + 64]     = a11[g];
            part[(pw + 4 + g) * 128 + bl]      = a20[g];
            part[(pw + 4 + g) * 128 + bl + 64] = a21[g];
        }
        __syncthreads();

        // ---- finish: thread (fu, fb) -> unit jb+fu, batch bx ----
        if (doL1) {
            float g4[4];
            #pragma unroll
            for (int g = 0; g < 4; ++g) {
                float acc = b1r[g] + part[(pb0 + g) * 128 + fb] + part[(pb1 + g) * 128 + fb];
                #pragma unroll
                for (int i = 0; i < INx; ++i) acc += xv[i] * wx1l[(fu * 4 + g) * 20 + i];
                g4[g] = acc;
            }
            const float ig = sigf(g4[0]), fg = sigf(g4[1]);
            const float gg = tanhfast(g4[2]), og = sigf(g4[3]);
            c1 = fg * c1 + ig * gg;
            gstore(&h1n[(jb + fu) * Bb + bx], og * tanhfast(c1));
        }
        {
            float g4[4];
            #pragma unroll
            for (int g = 0; g < 4; ++g)
                g4[g] = b2r[g] + part[(pb0 + 4 + g) * 128 + fb] + part[(pb1 + 4 + g) * 128 + fb];
            const float ig = sigf(g4[0]), fg = sigf(g4[1]);
            const float gg = tanhfast(g4[2]), og = sigf(g4[3]);
            c2 = fg * c2 + ig * gg;
            gstore(&h2n[(jb + fu) * Bb + bx], og * tanhfast(c2));
        }

        gbar(flags, wgid, tid, (u32)(t + 2));

        const float* tp = h1c; h1c = h1n; h1n = (float*)tp;
        tp = h2c; h2c = h2n; h2n = (float*)tp;
    }
    // final h2 in h2c

    // ---------- FC head: WG wgid handles batch wgid; reuse `part` LDS ----------
    float* hh  = part;             // 512
    float* a1s = part + Hh;        // 256
    float* a2s = part + Hh + 256;  // 128
    hh[tid] = h2c[tid * Bb + wgid];
    __syncthreads();
    if (tid < 256) {
        float acc = fc1_b[tid];
        const float* wr = fc1_W + (size_t)tid * Hh;
        for (int i = 0; i < Hh; ++i) acc += wr[i] * hh[i];
        a1s[tid] = fmaxf(acc, 0.0f);
    }
    __syncthreads();
    if (tid < 128) {
        float acc = fc2_b[tid];
        const float* wr = fc2_W + (size_t)tid * 256;
        for (int i = 0; i < 256; ++i) acc += wr[i] * a1s[i];
        a2s[tid] = fmaxf(acc, 0.0f);
    }
    __syncthreads();
    if (tid == 0) {
        float acc = fc3_b[0];
        for (int i = 0; i < 128; ++i) acc += fc3_W[i] * a2s[i];
        out[wgid] = acc;
    }
}

extern "C" void kernel_launch(void* const* d_in, const int* in_sizes, int n_in,
                              void* d_out, int out_size, void* d_ws, size_t ws_size,
                              hipStream_t stream)
{
    (void)in_sizes; (void)n_in; (void)out_size; (void)ws_size;

    const float* input = (const float*)d_in[0];
    const float* l1_Wx = (const float*)d_in[1];
    const float* l1_bx = (const float*)d_in[2];
    const float* l1_Wh = (const float*)d_in[3];
    const float* l1_bh = (const float*)d_in[4];
    const float* l2_Wx = (const float*)d_in[5];
    const float* l2_bx = (const float*)d_in[6];
    const float* l2_Wh = (const float*)d_in[7];
    const float* l2_bh = (const float*)d_in[8];
    const float* fc1_W = (const float*)d_in[9];
    const float* fc1_b = (const float*)d_in[10];
    const float* fc2_W = (const float*)d_in[11];
    const float* fc2_b = (const float*)d_in[12];
    const float* fc3_W = (const float*)d_in[13];
    const float* fc3_b = (const float*)d_in[14];
    float* out = (float*)d_out;
    float* ws  = (float*)d_ws;

    // allow >64KB dynamic LDS (idempotent; safe under graph capture)
    hipFuncSetAttribute((const void*)lstm_fused,
                        hipFuncAttributeMaxDynamicSharedMemorySize, SMEM_BYTES);

    void* args[] = {
        &input,
        &l1_Wx, &l1_bx, &l1_Wh, &l1_bh,
        &l2_Wx, &l2_bx, &l2_Wh, &l2_bh,
        &fc1_W, &fc1_b, &fc2_W, &fc2_b, &fc3_W, &fc3_b,
        &out, &ws
    };
    hipLaunchCooperativeKernel((void*)lstm_fused, dim3(NWG), dim3(NTHR), args,
                               SMEM_BYTES, stream);
}

// Round 6
// 65527.283 us; speedup vs baseline: 2.3490x; 2.3490x over previous
//
#include <hip/hip_runtime.h>
#include <hip/hip_cooperative_groups.h>

namespace cg = cooperative_groups;

#define Bb   256   // batch
#define Tt   512   // time steps
#define INx  19    // input features
#define Hh   512   // hidden
#define NWG  256   // workgroups: (unit-group 0..63) x (batch-half 0..1)? -> ug=wgid>>1 (0..127)*4 units
#define NTHR 512   // threads: sweep (kq 0..3)x(bl 0..127); finish (fu 0..3)x(fb 0..127)

#define PART_FLOATS (4 * 48 * 128)   // [kq][48 rows][128 b] = 98304 B
#define WX1_FLOATS  (16 * 20)        // l1_Wx rows (4u x 4g) padded to 20
#define SMEM_FLOATS (PART_FLOATS + WX1_FLOATS)
#define SMEM_BYTES  (SMEM_FLOATS * 4)

typedef unsigned int u32;
typedef unsigned long long u64;

__device__ __forceinline__ float sigf(float x) { return 1.0f / (1.0f + __expf(-x)); }
__device__ __forceinline__ float tanhfast(float x) {
    float e = __expf(2.0f * x);
    return 1.0f - 2.0f / (e + 1.0f);
}

union pcast { u64 u; float2 f; };

// Uncached (LLC-coherent) 8B pair load/store: h never sits in L1/L2, so the
// cached weights/x NEVER need an invalidating acquire fence.
__device__ __forceinline__ float2 gload2(const float2* p) {
    pcast c;
    c.u = __hip_atomic_load((const u64*)p, __ATOMIC_RELAXED, __HIP_MEMORY_SCOPE_AGENT);
    return c.f;
}
__device__ __forceinline__ void gstore2(float2* p, float2 v) {
    pcast c; c.f = v;
    __hip_atomic_store((u64*)p, c.u, __ATOMIC_RELAXED, __HIP_MEMORY_SCOPE_AGENT);
}

// Flag barrier with NO cache invalidation (nothing cached is ever written).
__device__ __forceinline__ void gbar(u32* flags, int wgid, int tid, u32 phase) {
    __syncthreads();   // compiler drains vmcnt before s_barrier -> h stores at LLC
    if (tid == 0)
        __hip_atomic_store(&flags[wgid], phase, __ATOMIC_RELEASE, __HIP_MEMORY_SCOPE_AGENT);
    if (tid < NWG) {
        const u32* fp = &flags[tid];
        while (__hip_atomic_load(fp, __ATOMIC_RELAXED, __HIP_MEMORY_SCOPE_AGENT) < phase)
            __builtin_amdgcn_s_sleep(2);
    }
    __syncthreads();
}

// WG (ug, bs): units jb..jb+3, batches bs*128..bs*128+127.
// h1/h2 stored as pairs P[j][b] = (h1[t+1], h2[t]) -- exactly what step t+1 reads.
// Weights are read via wave-uniform cached float4 loads (L2-hot forever).
__global__ void __launch_bounds__(NTHR, 2)
lstm_fused(const float* __restrict__ input,
           const float* __restrict__ l1_Wx, const float* __restrict__ l1_bx,
           const float* __restrict__ l1_Wh, const float* __restrict__ l1_bh,
           const float* __restrict__ l2_Wx, const float* __restrict__ l2_bx,
           const float* __restrict__ l2_Wh, const float* __restrict__ l2_bh,
           const float* __restrict__ fc1_W, const float* __restrict__ fc1_b,
           const float* __restrict__ fc2_W, const float* __restrict__ fc2_b,
           const float* __restrict__ fc3_W, const float* __restrict__ fc3_b,
           float* __restrict__ out, float* __restrict__ ws)
{
    extern __shared__ float smem[];
    float* part = smem;                    // [4][48][128] b32, stride-1 -> conflict-free
    float* wx1l = smem + PART_FLOATS;      // [16][20]

    cg::grid_group grid = cg::this_grid();
    const int wgid = blockIdx.x;
    const int ug = wgid >> 1;              // 0..127
    const int bs = wgid & 1;
    const int jb = ug * 4;
    const int tid = threadIdx.x;
    const int kq = tid >> 7;               // sweep: K-quarter
    const int fu = tid >> 7;               // finish: unit-in-group
    const int fb = tid & 127;
    const int bx = bs * 128 + fb;          // this thread's batch (both roles)

    float2* PA = (float2*)ws;
    float2* PB = PA + (size_t)Hh * Bb;
    u32* flags = (u32*)(PB + (size_t)Hh * Bb);

    // ---- reset flags (replay-safe), then the only cg sync ----
    if (tid == 0)
        __hip_atomic_store(&flags[wgid], 0u, __ATOMIC_RELAXED, __HIP_MEMORY_SCOPE_AGENT);
    grid.sync();

    // ---- stage l1_Wx rows + biases (cached reads; stay hot) ----
    if (tid < 16 * INx) {
        const int r = tid / INx, i = tid - r * INx;
        const int u = r >> 2, g = r & 3;
        wx1l[r * 20 + i] = l1_Wx[(size_t)(g * Hh + jb + u) * INx + i];
    }
    float b1r[4], b2r[4];
    #pragma unroll
    for (int g = 0; g < 4; ++g) {
        const int row = g * Hh + jb + fu;
        b1r[g] = l1_bx[row] + l1_bh[row];
        b2r[g] = l2_bx[row] + l2_bh[row];
    }
    __syncthreads();

    // ---- prologue: P = (h1[0], h2[-1]=0) ----
    float c1 = 0.f, c2 = 0.f;
    {
        const float* xr = input + (size_t)bx * Tt * INx;
        float g4[4];
        #pragma unroll
        for (int g = 0; g < 4; ++g) {
            float acc = b1r[g];
            #pragma unroll
            for (int i = 0; i < INx; ++i) acc += xr[i] * wx1l[(fu * 4 + g) * 20 + i];
            g4[g] = acc;
        }
        c1 = sigf(g4[0]) * tanhfast(g4[2]);
        const float h1v = sigf(g4[3]) * tanhfast(c1);
        gstore2(&PA[(size_t)(jb + fu) * Bb + bx], make_float2(h1v, 0.f));
    }
    gbar(flags, wgid, tid, 1u);

    const float2* Pc = PA; float2* Pn = PB;

    #pragma unroll 1
    for (int t = 0; t < Tt; ++t) {
        const bool doL1 = (t < Tt - 1);

        // ---------- sweep: 48 rows x K=128 x 1 batch ----------
        float a1[4][4], ax[4][4], ah[4][4];
        #pragma unroll
        for (int u = 0; u < 4; ++u)
            #pragma unroll
            for (int g = 0; g < 4; ++g) { a1[u][g] = 0.f; ax[u][g] = 0.f; ah[u][g] = 0.f; }

        const int k0 = kq << 7;
        const float2* hp = Pc + (size_t)k0 * Bb + bx;

        float2 hc[4], hn[4];
        #pragma unroll
        for (int j = 0; j < 4; ++j) hc[j] = gload2(hp + (size_t)j * Bb);

        #pragma unroll 1
        for (int c = 0; c < 32; ++c) {
            if (c < 31) {
                #pragma unroll
                for (int j = 0; j < 4; ++j)
                    hn[j] = gload2(hp + (size_t)(c * 4 + 4 + j) * Bb);
            }
            const int k4 = k0 + c * 4;
            #pragma unroll
            for (int u = 0; u < 4; ++u) {
                const size_t rbu = (size_t)(jb + u) * Hh + k4;
                #pragma unroll
                for (int g = 0; g < 4; ++g) {
                    const size_t ro = (size_t)g * (Hh * Hh) + rbu;   // (g*Hh + jb+u)*Hh + k4
                    const float4 w1 = *reinterpret_cast<const float4*>(l1_Wh + ro);
                    a1[u][g] += hc[0].x*w1.x + hc[1].x*w1.y + hc[2].x*w1.z + hc[3].x*w1.w;
                    const float4 w2 = *reinterpret_cast<const float4*>(l2_Wx + ro);
                    ax[u][g] += hc[0].x*w2.x + hc[1].x*w2.y + hc[2].x*w2.z + hc[3].x*w2.w;
                    const float4 w3 = *reinterpret_cast<const float4*>(l2_Wh + ro);
                    ah[u][g] += hc[0].y*w3.x + hc[1].y*w3.y + hc[2].y*w3.z + hc[3].y*w3.w;
                }
            }
            #pragma unroll
            for (int j = 0; j < 4; ++j) hc[j] = hn[j];
        }

        // write partials: part[kq][u*12 + ty*4 + g][bl], stride-1 over lanes
        {
            float* pw = part + ((size_t)kq * 48) * 128 + fb;
            #pragma unroll
            for (int u = 0; u < 4; ++u)
                #pragma unroll
                for (int g = 0; g < 4; ++g) {
                    pw[(u * 12 + 0 + g) * 128] = a1[u][g];
                    pw[(u * 12 + 4 + g) * 128] = ax[u][g];
                    pw[(u * 12 + 8 + g) * 128] = ah[u][g];
                }
        }

        // x[t+1] for the finish phase (cached, L2-hot; issued before the sync)
        float xv[INx];
        if (doL1) {
            const float* xr = input + ((size_t)bx * Tt + t + 1) * INx;
            #pragma unroll
            for (int i = 0; i < INx; ++i) xv[i] = xr[i];
        }
        __syncthreads();

        // ---------- finish: unit jb+fu, batch bx ----------
        const float* pr = part + fb;
        float h1v = 0.f;
        if (doL1) {
            float g4[4];
            #pragma unroll
            for (int g = 0; g < 4; ++g) {
                float acc = b1r[g];
                #pragma unroll
                for (int q = 0; q < 4; ++q)
                    acc += pr[((size_t)q * 48 + fu * 12 + 0 + g) * 128];
                #pragma unroll
                for (int i = 0; i < INx; ++i) acc += xv[i] * wx1l[(fu * 4 + g) * 20 + i];
                g4[g] = acc;
            }
            const float ig = sigf(g4[0]), fg = sigf(g4[1]);
            const float gg = tanhfast(g4[2]), og = sigf(g4[3]);
            c1 = fg * c1 + ig * gg;
            h1v = og * tanhfast(c1);
        }
        {
            float g4[4];
            #pragma unroll
            for (int g = 0; g < 4; ++g) {
                float acc = b2r[g];
                #pragma unroll
                for (int q = 0; q < 4; ++q)
                    acc += pr[((size_t)q * 48 + fu * 12 + 4 + g) * 128]
                         + pr[((size_t)q * 48 + fu * 12 + 8 + g) * 128];
                g4[g] = acc;
            }
            const float ig = sigf(g4[0]), fg = sigf(g4[1]);
            const float gg = tanhfast(g4[2]), og = sigf(g4[3]);
            c2 = fg * c2 + ig * gg;
            const float h2v = og * tanhfast(c2);
            gstore2(&Pn[(size_t)(jb + fu) * Bb + bx], make_float2(h1v, h2v));
        }

        gbar(flags, wgid, tid, (u32)(t + 2));

        const float2* tp = Pc; Pc = Pn; Pn = (float2*)tp;
    }
    // final pair buffer = Pc; .y = h2[511]

    // ---------- FC head: WG wgid handles batch wgid (reuse smem) ----------
    float* hh  = smem;             // 512
    float* a1s = smem + Hh;        // 256
    float* a2s = smem + Hh + 256;  // 128
    hh[tid] = gload2(&Pc[(size_t)tid * Bb + wgid]).y;
    __syncthreads();
    if (tid < 256) {
        float acc = fc1_b[tid];
        const float* wr = fc1_W + (size_t)tid * Hh;
        for (int i = 0; i < Hh; ++i) acc += wr[i] * hh[i];
        a1s[tid] = fmaxf(acc, 0.0f);
    }
    __syncthreads();
    if (tid < 128) {
        float acc = fc2_b[tid];
        const float* wr = fc2_W + (size_t)tid * 256;
        for (int i = 0; i < 256; ++i) acc += wr[i] * a1s[i];
        a2s[tid] = fmaxf(acc, 0.0f);
    }
    __syncthreads();
    if (tid == 0) {
        float acc = fc3_b[0];
        for (int i = 0; i < 128; ++i) acc += fc3_W[i] * a2s[i];
        out[wgid] = acc;
    }
}

extern "C" void kernel_launch(void* const* d_in, const int* in_sizes, int n_in,
                              void* d_out, int out_size, void* d_ws, size_t ws_size,
                              hipStream_t stream)
{
    (void)in_sizes; (void)n_in; (void)out_size; (void)ws_size;

    const float* input = (const float*)d_in[0];
    const float* l1_Wx = (const float*)d_in[1];
    const float* l1_bx = (const float*)d_in[2];
    const float* l1_Wh = (const float*)d_in[3];
    const float* l1_bh = (const float*)d_in[4];
    const float* l2_Wx = (const float*)d_in[5];
    const float* l2_bx = (const float*)d_in[6];
    const float* l2_Wh = (const float*)d_in[7];
    const float* l2_bh = (const float*)d_in[8];
    const float* fc1_W = (const float*)d_in[9];
    const float* fc1_b = (const float*)d_in[10];
    const float* fc2_W = (const float*)d_in[11];
    const float* fc2_b = (const float*)d_in[12];
    const float* fc3_W = (const float*)d_in[13];
    const float* fc3_b = (const float*)d_in[14];
    float* out = (float*)d_out;
    float* ws  = (float*)d_ws;

    hipFuncSetAttribute((const void*)lstm_fused,
                        hipFuncAttributeMaxDynamicSharedMemorySize, SMEM_BYTES);

    void* args[] = {
        &input,
        &l1_Wx, &l1_bx, &l1_Wh, &l1_bh,
        &l2_Wx, &l2_bx, &l2_Wh, &l2_bh,
        &fc1_W, &fc1_b, &fc2_W, &fc2_b, &fc3_W, &fc3_b,
        &out, &ws
    };
    hipLaunchCooperativeKernel((void*)lstm_fused, dim3(NWG), dim3(NTHR), args,
                               SMEM_BYTES, stream);
}

// Round 7
// 30441.696 us; speedup vs baseline: 5.0563x; 2.1526x over previous
//
#include <hip/hip_runtime.h>
#include <hip/hip_cooperative_groups.h>

namespace cg = cooperative_groups;

#define Bb   256   // batch
#define Tt   512   // time steps
#define INx  19    // input features
#define Hh   512   // hidden
#define NWG  256   // workgroups: wg owns units {2w, 2w+1}, all 256 batches
#define NTHR 512   // 8 waves: (su 0..1) x (bh 0..3); lane = (kq 0..3) x (bg 0..15)

typedef unsigned int u32;
typedef unsigned long long u64;

__device__ __forceinline__ float sigf(float x) { return 1.0f / (1.0f + __expf(-x)); }
__device__ __forceinline__ float tanhfast(float x) {
    float e = __expf(2.0f * x);
    return 1.0f - 2.0f / (e + 1.0f);
}

union pcast { u64 u; float2 f; };
// h stores bypass L1/L2 -> LLC; reads are CACHED and refreshed by the
// acquire fence in gbar (weights are in LDS -> immune to the invalidate).
__device__ __forceinline__ void gstore2(float2* p, float2 v) {
    pcast c; c.f = v;
    __hip_atomic_store((u64*)p, c.u, __ATOMIC_RELAXED, __HIP_MEMORY_SCOPE_AGENT);
}

__device__ __forceinline__ void gbar(u32* flags, int wgid, int tid, u32 phase) {
    __syncthreads();   // drains vmem stores of all waves before flag release
    if (tid == 0)
        __hip_atomic_store(&flags[wgid], phase, __ATOMIC_RELEASE, __HIP_MEMORY_SCOPE_AGENT);
    if (tid < NWG) {
        const u32* fp = &flags[tid];
        while (__hip_atomic_load(fp, __ATOMIC_RELAXED, __HIP_MEMORY_SCOPE_AGENT) < phase)
            __builtin_amdgcn_s_sleep(2);
    }
    __syncthreads();
    __builtin_amdgcn_fence(__ATOMIC_ACQUIRE, "agent");   // L1/L2 refetch of h
}

// load chunk c: 4 consecutive k's, 4 batches each as 2 float4 (pairs h1,h2)
__device__ __forceinline__ void ldh(const float4* __restrict__ hp, int c,
                                    float4 (&A)[4], float4 (&B)[4]) {
    #pragma unroll
    for (int kk = 0; kk < 4; ++kk) {
        A[kk] = hp[(size_t)(c * 4 + kk) * 128];
        B[kk] = hp[(size_t)(c * 4 + kk) * 128 + 1];
    }
}

// 192 FMAs: 4 gates x 3 matrices x 4 k x 4 batches.
// A[kk]: batches b0,b1 -> (h1=.x,h2=.y,h1=.z,h2=.w); B[kk]: b2,b3.
__device__ __forceinline__ void fmac(const float4 (&A)[4], const float4 (&B)[4],
                                     const float* __restrict__ wk,
                                     float (&a1)[4][4], float (&ax)[4][4], float (&ah)[4][4]) {
    #pragma unroll
    for (int g = 0; g < 4; ++g) {
        const float4 w1 = *reinterpret_cast<const float4*>(wk + (0 + g) * 528);
        const float4 w2 = *reinterpret_cast<const float4*>(wk + (4 + g) * 528);
        const float4 w3 = *reinterpret_cast<const float4*>(wk + (8 + g) * 528);
        a1[g][0] += A[0].x*w1.x + A[1].x*w1.y + A[2].x*w1.z + A[3].x*w1.w;
        a1[g][1] += A[0].z*w1.x + A[1].z*w1.y + A[2].z*w1.z + A[3].z*w1.w;
        a1[g][2] += B[0].x*w1.x + B[1].x*w1.y + B[2].x*w1.z + B[3].x*w1.w;
        a1[g][3] += B[0].z*w1.x + B[1].z*w1.y + B[2].z*w1.z + B[3].z*w1.w;
        ax[g][0] += A[0].x*w2.x + A[1].x*w2.y + A[2].x*w2.z + A[3].x*w2.w;
        ax[g][1] += A[0].z*w2.x + A[1].z*w2.y + A[2].z*w2.z + A[3].z*w2.w;
        ax[g][2] += B[0].x*w2.x + B[1].x*w2.y + B[2].x*w2.z + B[3].x*w2.w;
        ax[g][3] += B[0].z*w2.x + B[1].z*w2.y + B[2].z*w2.z + B[3].z*w2.w;
        ah[g][0] += A[0].y*w3.x + A[1].y*w3.y + A[2].y*w3.z + A[3].y*w3.w;
        ah[g][1] += A[0].w*w3.x + A[1].w*w3.y + A[2].w*w3.z + A[3].w*w3.w;
        ah[g][2] += B[0].y*w3.x + B[1].y*w3.y + B[2].y*w3.z + B[3].y*w3.w;
        ah[g][3] += B[0].w*w3.x + B[1].w*w3.y + B[2].w*w3.z + B[3].w*w3.w;
    }
}

__global__ void __launch_bounds__(NTHR, 2)
lstm_fused(const float* __restrict__ input,
           const float* __restrict__ l1_Wx, const float* __restrict__ l1_bx,
           const float* __restrict__ l1_Wh, const float* __restrict__ l1_bh,
           const float* __restrict__ l2_Wx, const float* __restrict__ l2_bx,
           const float* __restrict__ l2_Wh, const float* __restrict__ l2_bh,
           const float* __restrict__ fc1_W, const float* __restrict__ fc1_b,
           const float* __restrict__ fc2_W, const float* __restrict__ fc2_b,
           const float* __restrict__ fc3_W, const float* __restrict__ fc3_b,
           float* __restrict__ out, float* __restrict__ ws)
{
    // weights: [row 0..23][kq 0..3][132 (128 + 4 pad)] -> 4 kq addr groups hit
    // disjoint banks (528 floats = bank shift 4); 16-lane groups broadcast.
    __shared__ float wlds[24 * 528];         // 50688 B
    __shared__ float wx1l[8 * 20];           // l1_Wx rows (2 su x 4 g), pad 20
    __shared__ float fcb[Hh + 256 + 128];    // FC head scratch

    cg::grid_group grid = cg::this_grid();
    const int wgid = blockIdx.x;
    const int jb = wgid * 2;
    const int tid = threadIdx.x;
    const int wid = tid >> 6, lane = tid & 63;
    const int su = wid & 1;              // unit select (0/1)
    const int bh = wid >> 1;             // batch block (0..3)
    const int kq = lane >> 4;            // K quarter (0..3)
    const int bg = lane & 15;
    const int bB = bh * 64 + bg * 4;     // first of this lane's 4 batches
    const int j  = jb + su;              // owned unit

    float2* PA = (float2*)ws;            // P[j][b] = (h1, h2) pairs
    float2* PB = PA + Hh * Bb;
    u32* flags = (u32*)(PB + Hh * Bb);

    if (tid == 0)
        __hip_atomic_store(&flags[wgid], 0u, __ATOMIC_RELAXED, __HIP_MEMORY_SCOPE_AGENT);
    grid.sync();   // fences flag resets; the only runtime cg sync

    // ---- stage weights into LDS (once) ----
    for (int idx = tid; idx < 24 * 512; idx += NTHR) {
        const int row = idx >> 9, k = idx & 511;
        const int sru = row >= 12 ? 1 : 0;
        const int rr = row - sru * 12;
        const int m = rr >> 2, g = rr & 3;
        const float* src = (m == 0) ? l1_Wh : (m == 1) ? l2_Wx : l2_Wh;
        wlds[row * 528 + (k >> 7) * 132 + (k & 127)] =
            src[(size_t)(g * Hh + jb + sru) * Hh + k];
    }
    if (tid < 8 * INx) {
        const int r = tid / INx, i = tid - r * INx;
        const int sru = r >> 2, g = r & 3;
        wx1l[r * 20 + i] = l1_Wx[(size_t)(g * Hh + jb + sru) * INx + i];
    }
    float b1r[4], b2r[4];
    #pragma unroll
    for (int g = 0; g < 4; ++g) {
        const int row = g * Hh + j;
        b1r[g] = l1_bx[row] + l1_bh[row];
        b2r[g] = l2_bx[row] + l2_bh[row];
    }
    __syncthreads();

    // ---- prologue: h1[0] from x[0]; c=0; P = (h1[0], 0) ----
    float c1[4], c2[4];
    #pragma unroll
    for (int b = 0; b < 4; ++b) {
        const float* xr = input + (size_t)(bB + b) * Tt * INx;
        float s[4];
        #pragma unroll
        for (int g = 0; g < 4; ++g) {
            float acc = b1r[g];
            #pragma unroll
            for (int i = 0; i < INx; ++i) acc += xr[i] * wx1l[(su * 4 + g) * 20 + i];
            s[g] = acc;
        }
        c1[b] = sigf(s[0]) * tanhfast(s[2]);        // f*0 + i*g
        c2[b] = 0.0f;
        const float h1v = sigf(s[3]) * tanhfast(c1[b]);
        if (kq == 0) gstore2(&PA[(size_t)j * Bb + bB + b], make_float2(h1v, 0.0f));
    }
    gbar(flags, wgid, tid, 1u);

    const float2* Pc = PA; float2* Pn = PB;
    const float* wlane = wlds + su * (12 * 528) + kq * 132;

    for (int t = 0; t < Tt; ++t) {
        const bool doL1 = (t < Tt - 1);

        float a1[4][4], ax[4][4], ah[4][4];
        #pragma unroll
        for (int g = 0; g < 4; ++g)
            #pragma unroll
            for (int b = 0; b < 4; ++b) { a1[g][b] = 0.f; ax[g][b] = 0.f; ah[g][b] = 0.f; }

        // lane's float4 base: pair index (k*256 + bB), k = kq*128 + ...
        const float4* hp = (const float4*)Pc + (size_t)(kq * 128) * 128 + (bB >> 1);

        float4 Ac[4], Bc[4], An[4], Bn[4];
        ldh(hp, 0, Ac, Bc);
        #pragma unroll 1
        for (int c = 0; c < 32; c += 2) {
            ldh(hp, c + 1, An, Bn);                   // prefetch odd chunk
            fmac(Ac, Bc, wlane + c * 4, a1, ax, ah);
            if (c < 30) ldh(hp, c + 2, Ac, Bc);       // prefetch next even chunk
            fmac(An, Bn, wlane + (c + 1) * 4, a1, ax, ah);
        }

        // ---- butterfly K-reduce over the 4 kq groups (lane bits 4,5) ----
        #pragma unroll
        for (int g = 0; g < 4; ++g) {
            #pragma unroll
            for (int b = 0; b < 4; ++b) {
                float v = a1[g][b]; v += __shfl_xor(v, 16, 64); v += __shfl_xor(v, 32, 64); a1[g][b] = v;
                float w = ax[g][b]; w += __shfl_xor(w, 16, 64); w += __shfl_xor(w, 32, 64); ax[g][b] = w;
                float u = ah[g][b]; u += __shfl_xor(u, 16, 64); u += __shfl_xor(u, 32, 64); ah[g][b] = u;
            }
        }

        // ---- finish: all lanes track gates (kq copies identical); kq==0 stores ----
        #pragma unroll
        for (int b = 0; b < 4; ++b) {
            float s2[4];
            #pragma unroll
            for (int g = 0; g < 4; ++g) s2[g] = ax[g][b] + ah[g][b] + b2r[g];

            float h1v = 0.0f;
            if (doL1) {
                const float* xr = input + ((size_t)(bB + b) * Tt + (t + 1)) * INx;
                float s1[4];
                #pragma unroll
                for (int g = 0; g < 4; ++g) {
                    float acc = a1[g][b] + b1r[g];
                    #pragma unroll
                    for (int i = 0; i < INx; ++i) acc += xr[i] * wx1l[(su * 4 + g) * 20 + i];
                    s1[g] = acc;
                }
                const float ig = sigf(s1[0]), fg = sigf(s1[1]);
                const float gg = tanhfast(s1[2]), og = sigf(s1[3]);
                c1[b] = fg * c1[b] + ig * gg;
                h1v = og * tanhfast(c1[b]);
            }
            const float ig = sigf(s2[0]), fg = sigf(s2[1]);
            const float gg = tanhfast(s2[2]), og = sigf(s2[3]);
            c2[b] = fg * c2[b] + ig * gg;
            const float h2v = og * tanhfast(c2[b]);
            if (kq == 0) gstore2(&Pn[(size_t)j * Bb + bB + b], make_float2(h1v, h2v));
        }

        gbar(flags, wgid, tid, (u32)(t + 2));

        const float2* tp = Pc; Pc = Pn; Pn = (float2*)tp;
    }
    // final h2 = Pc[.].y

    // ---------- FC head: WG wgid handles batch wgid ----------
    float* hh  = fcb;
    float* a1s = fcb + Hh;
    float* a2s = fcb + Hh + 256;
    hh[tid] = Pc[(size_t)tid * Bb + wgid].y;   // cached, fresh post-fence
    __syncthreads();
    if (tid < 256) {
        float acc = fc1_b[tid];
        const float* wr = fc1_W + (size_t)tid * Hh;
        for (int i = 0; i < Hh; ++i) acc += wr[i] * hh[i];
        a1s[tid] = fmaxf(acc, 0.0f);
    }
    __syncthreads();
    if (tid < 128) {
        float acc = fc2_b[tid];
        const float* wr = fc2_W + (size_t)tid * 256;
        for (int i = 0; i < 256; ++i) acc += wr[i] * a1s[i];
        a2s[tid] = fmaxf(acc, 0.0f);
    }
    __syncthreads();
    if (tid == 0) {
        float acc = fc3_b[0];
        for (int i = 0; i < 128; ++i) acc += fc3_W[i] * a2s[i];
        out[wgid] = acc;
    }
}

extern "C" void kernel_launch(void* const* d_in, const int* in_sizes, int n_in,
                              void* d_out, int out_size, void* d_ws, size_t ws_size,
                              hipStream_t stream)
{
    (void)in_sizes; (void)n_in; (void)out_size; (void)ws_size;

    const float* input = (const float*)d_in[0];
    const float* l1_Wx = (const float*)d_in[1];
    const float* l1_bx = (const float*)d_in[2];
    const float* l1_Wh = (const float*)d_in[3];
    const float* l1_bh = (const float*)d_in[4];
    const float* l2_Wx = (const float*)d_in[5];
    const float* l2_bx = (const float*)d_in[6];
    const float* l2_Wh = (const float*)d_in[7];
    const float* l2_bh = (const float*)d_in[8];
    const float* fc1_W = (const float*)d_in[9];
    const float* fc1_b = (const float*)d_in[10];
    const float* fc2_W = (const float*)d_in[11];
    const float* fc2_b = (const float*)d_in[12];
    const float* fc3_W = (const float*)d_in[13];
    const float* fc3_b = (const float*)d_in[14];
    float* out = (float*)d_out;
    float* ws  = (float*)d_ws;

    void* args[] = {
        &input,
        &l1_Wx, &l1_bx, &l1_Wh, &l1_bh,
        &l2_Wx, &l2_bx, &l2_Wh, &l2_bh,
        &fc1_W, &fc1_b, &fc2_W, &fc2_b, &fc3_W, &fc3_b,
        &out, &ws
    };
    hipLaunchCooperativeKernel((void*)lstm_fused, dim3(NWG), dim3(NTHR), args, 0, stream);
}

// Round 9
// 29857.001 us; speedup vs baseline: 5.1554x; 1.0196x over previous
//
#include <hip/hip_runtime.h>
#include <hip/hip_cooperative_groups.h>

namespace cg = cooperative_groups;

#define Bb   256   // batch
#define Tt   512   // time steps
#define INx  19    // input features
#define Hh   512   // hidden
#define NWG  256   // workgroups (2 units each) -- cooperative-launch proven size
#define NTHR 512   // 8 waves = (kq 0..3) x (su 0..1); lane = bg 0..63 (4 batches)

#define PART_FLOATS (8 * 12 * 256)       // [su*4+kq][12 rows][256 b] = 98304 B
#define WX1_FLOATS  (8 * 20)             // 2 units x 4 gates x 19 (pad 20)
#define FCB_FLOATS  (Hh + 256 + 128)
#define SMEM_FLOATS (PART_FLOATS + WX1_FLOATS + FCB_FLOATS)
#define SMEM_BYTES  (SMEM_FLOATS * 4)

typedef unsigned int u32;
typedef unsigned long long u64;

__device__ __forceinline__ float sigf(float x) { return 1.0f / (1.0f + __expf(-x)); }
__device__ __forceinline__ float tanhfast(float x) {
    float e = __expf(2.0f * x);
    return 1.0f - 2.0f / (e + 1.0f);
}

union pcast { u64 u; float2 f; };
// h stores bypass L1/L2 -> LLC; reads are cached and refreshed by the acquire
// fence in gbar. Weights are read-only, so their cache state is always valid.
__device__ __forceinline__ void gstore2(float2* p, float2 v) {
    pcast c; c.f = v;
    __hip_atomic_store((u64*)p, c.u, __ATOMIC_RELAXED, __HIP_MEMORY_SCOPE_AGENT);
}

__device__ __forceinline__ void gbar(u32* flags, int wgid, int tid, u32 phase) {
    __syncthreads();   // drains vmem stores of all waves before flag release
    if (tid == 0)
        __hip_atomic_store(&flags[wgid], phase, __ATOMIC_RELEASE, __HIP_MEMORY_SCOPE_AGENT);
    if (tid < NWG) {
        const u32* fp = &flags[tid];
        while (__hip_atomic_load(fp, __ATOMIC_RELAXED, __HIP_MEMORY_SCOPE_AGENT) < phase)
            __builtin_amdgcn_s_sleep(2);
    }
    __syncthreads();
    __builtin_amdgcn_fence(__ATOMIC_ACQUIRE, "agent");   // h refetch (L1/L2 inv)
}

// load chunk c: 4 consecutive k's, this lane's 4 batches as 2 float4 per k
__device__ __forceinline__ void ldh(const float4* __restrict__ hp, int c,
                                    float4 (&A)[4], float4 (&B)[4]) {
    #pragma unroll
    for (int kk = 0; kk < 4; ++kk) {
        A[kk] = hp[(size_t)(c * 4 + kk) * 128];
        B[kk] = hp[(size_t)(c * 4 + kk) * 128 + 1];
    }
}

// 192 FMA: 12 rows x 4 k x 4 batches. Weight pointers are WAVE-UNIFORM
// (built from readfirstlane'd su/kq) -> s_load_dwordx4, SGPR operands.
// A[kk]: batches b0,b1 as (h1,h2,h1,h2); B[kk]: b2,b3.
__device__ __forceinline__ void fmac(const float4 (&A)[4], const float4 (&B)[4],
                                     const float* const (&wb1)[4],
                                     const float* const (&wb2)[4],
                                     const float* const (&wb3)[4], int c4,
                                     float (&a1)[4][4], float (&ax)[4][4], float (&ah)[4][4]) {
    #pragma unroll
    for (int g = 0; g < 4; ++g) {
        const float4 w1 = *reinterpret_cast<const float4*>(wb1[g] + c4);
        const float4 w2 = *reinterpret_cast<const float4*>(wb2[g] + c4);
        const float4 w3 = *reinterpret_cast<const float4*>(wb3[g] + c4);
        a1[g][0] += A[0].x*w1.x + A[1].x*w1.y + A[2].x*w1.z + A[3].x*w1.w;
        a1[g][1] += A[0].z*w1.x + A[1].z*w1.y + A[2].z*w1.z + A[3].z*w1.w;
        a1[g][2] += B[0].x*w1.x + B[1].x*w1.y + B[2].x*w1.z + B[3].x*w1.w;
        a1[g][3] += B[0].z*w1.x + B[1].z*w1.y + B[2].z*w1.z + B[3].z*w1.w;
        ax[g][0] += A[0].x*w2.x + A[1].x*w2.y + A[2].x*w2.z + A[3].x*w2.w;
        ax[g][1] += A[0].z*w2.x + A[1].z*w2.y + A[2].z*w2.z + A[3].z*w2.w;
        ax[g][2] += B[0].x*w2.x + B[1].x*w2.y + B[2].x*w2.z + B[3].x*w2.w;
        ax[g][3] += B[0].z*w2.x + B[1].z*w2.y + B[2].z*w2.z + B[3].z*w2.w;
        ah[g][0] += A[0].y*w3.x + A[1].y*w3.y + A[2].y*w3.z + A[3].y*w3.w;
        ah[g][1] += A[0].w*w3.x + A[1].w*w3.y + A[2].w*w3.z + A[3].w*w3.w;
        ah[g][2] += B[0].y*w3.x + B[1].y*w3.y + B[2].y*w3.z + B[3].y*w3.w;
        ah[g][3] += B[0].w*w3.x + B[1].w*w3.y + B[2].w*w3.z + B[3].w*w3.w;
    }
}

__global__ void __launch_bounds__(NTHR, 2)
lstm_fused(const float* __restrict__ input,
           const float* __restrict__ l1_Wx, const float* __restrict__ l1_bx,
           const float* __restrict__ l1_Wh, const float* __restrict__ l1_bh,
           const float* __restrict__ l2_Wx, const float* __restrict__ l2_bx,
           const float* __restrict__ l2_Wh, const float* __restrict__ l2_bh,
           const float* __restrict__ fc1_W, const float* __restrict__ fc1_b,
           const float* __restrict__ fc2_W, const float* __restrict__ fc2_b,
           const float* __restrict__ fc3_W, const float* __restrict__ fc3_b,
           float* __restrict__ out, float* __restrict__ ws)
{
    extern __shared__ float smem[];
    float* part = smem;                        // [8][12][256] K-partial exchange
    float* wx1l = smem + PART_FLOATS;          // [2u][4g][20]
    float* fcb  = wx1l + WX1_FLOATS;

    cg::grid_group grid = cg::this_grid();
    const int wgid = blockIdx.x;
    const int jb = wgid * 2;
    const int tid = threadIdx.x;

    // sweep role: wave (su, kq), lane bg -> batches bg*4..+3, K quarter kq
    const int wu = __builtin_amdgcn_readfirstlane(tid >> 6);   // wave id, uniform
    const int su = wu & 1;           // unit select
    const int kq = wu >> 1;          // K quarter
    const int bg = tid & 63;
    // finish role: thread (su2, fb) -> unit jb+su2, batch fb
    const int su2 = tid >> 8;
    const int fb  = tid & 255;
    const int j2  = jb + su2;

    float2* PA = (float2*)ws;        // P[j][b] = (h1, h2)
    float2* PB = PA + Hh * Bb;
    u32* flags = (u32*)(PB + Hh * Bb);

    if (tid == 0)
        __hip_atomic_store(&flags[wgid], 0u, __ATOMIC_RELAXED, __HIP_MEMORY_SCOPE_AGENT);
    grid.sync();   // fences flag resets; the only runtime cg sync

    // ---- wave-uniform scalar weight row bases (s_load path) ----
    const float* wb1[4]; const float* wb2[4]; const float* wb3[4];
    {
        const int j = jb + su;
        #pragma unroll
        for (int g = 0; g < 4; ++g) {
            const size_t off = (size_t)(g * Hh + j) * Hh + kq * 128;
            wb1[g] = l1_Wh + off;
            wb2[g] = l2_Wx + off;
            wb3[g] = l2_Wh + off;
        }
    }

    // ---- stage tiny l1_Wx + biases (finish role) ----
    if (tid < 8 * INx) {
        const int r = tid / INx, i = tid - r * INx;
        const int u = r >> 2, g = r & 3;
        wx1l[r * 20 + i] = l1_Wx[(size_t)(g * Hh + jb + u) * INx + i];
    }
    float b1r[4], b2r[4];
    #pragma unroll
    for (int g = 0; g < 4; ++g) {
        const int row = g * Hh + j2;
        b1r[g] = l1_bx[row] + l1_bh[row];
        b2r[g] = l2_bx[row] + l2_bh[row];
    }
    __syncthreads();

    // ---- prologue: P = (h1[0], h2[-1]=0), finish role ----
    float c1 = 0.f, c2 = 0.f;
    {
        const float* xr = input + (size_t)fb * Tt * INx;
        float s[4];
        #pragma unroll
        for (int g = 0; g < 4; ++g) {
            float acc = b1r[g];
            #pragma unroll
            for (int i = 0; i < INx; ++i) acc += xr[i] * wx1l[(su2 * 4 + g) * 20 + i];
            s[g] = acc;
        }
        c1 = sigf(s[0]) * tanhfast(s[2]);
        gstore2(&PA[(size_t)j2 * Bb + fb], make_float2(sigf(s[3]) * tanhfast(c1), 0.f));
    }
    gbar(flags, wgid, tid, 1u);

    const float2* Pc = PA; float2* Pn = PB;
    const int blk = su * 4 + kq;     // partial rowset for this wave

    for (int t = 0; t < Tt; ++t) {
        const bool doL1 = (t < Tt - 1);

        float a1[4][4], ax[4][4], ah[4][4];
        #pragma unroll
        for (int g = 0; g < 4; ++g)
            #pragma unroll
            for (int b = 0; b < 4; ++b) { a1[g][b] = 0.f; ax[g][b] = 0.f; ah[g][b] = 0.f; }

        // lane's float4 base: f4 index = k*128 + bg*2, k = kq*128 + ...
        const float4* hp = (const float4*)Pc + (size_t)(kq * 128) * 128 + bg * 2;

        float4 E0[4], E1[4], O0[4], O1[4];
        ldh(hp, 0, E0, E1);
        #pragma unroll 1
        for (int c = 0; c < 32; c += 2) {
            ldh(hp, c + 1, O0, O1);
            fmac(E0, E1, wb1, wb2, wb3, (c    ) * 4, a1, ax, ah);
            if (c < 30) ldh(hp, c + 2, E0, E1);
            fmac(O0, O1, wb1, wb2, wb3, (c + 1) * 4, a1, ax, ah);
        }

        // ---- K-partial exchange: ds_write_b128, conflict-free ----
        {
            float* pw = part + (size_t)(blk * 12) * 256 + bg * 4;
            #pragma unroll
            for (int g = 0; g < 4; ++g) {
                *reinterpret_cast<float4*>(pw + (0 + g) * 256) = make_float4(a1[g][0], a1[g][1], a1[g][2], a1[g][3]);
                *reinterpret_cast<float4*>(pw + (4 + g) * 256) = make_float4(ax[g][0], ax[g][1], ax[g][2], ax[g][3]);
                *reinterpret_cast<float4*>(pw + (8 + g) * 256) = make_float4(ah[g][0], ah[g][1], ah[g][2], ah[g][3]);
            }
        }
        __syncthreads();

        // ---- finish: unit j2, batch fb; reduce 4 kq rowsets ----
        {
            float s1[4], s2[4];
            #pragma unroll
            for (int g = 0; g < 4; ++g) {
                float A1 = 0.f, AX = 0.f, AH = 0.f;
                #pragma unroll
                for (int q = 0; q < 4; ++q) {
                    const float* pr = part + (size_t)((su2 * 4 + q) * 12) * 256 + fb;
                    A1 += pr[(0 + g) * 256];
                    AX += pr[(4 + g) * 256];
                    AH += pr[(8 + g) * 256];
                }
                s1[g] = A1 + b1r[g];
                s2[g] = AX + AH + b2r[g];
            }
            float h1v = 0.f;
            if (doL1) {
                const float* xr = input + ((size_t)fb * Tt + t + 1) * INx;
                #pragma unroll
                for (int g = 0; g < 4; ++g) {
                    float acc = s1[g];
                    #pragma unroll
                    for (int i = 0; i < INx; ++i) acc += xr[i] * wx1l[(su2 * 4 + g) * 20 + i];
                    s1[g] = acc;
                }
                const float ig = sigf(s1[0]), fg = sigf(s1[1]);
                const float gg = tanhfast(s1[2]), og = sigf(s1[3]);
                c1 = fg * c1 + ig * gg;
                h1v = og * tanhfast(c1);
            }
            const float ig = sigf(s2[0]), fg = sigf(s2[1]);
            const float gg = tanhfast(s2[2]), og = sigf(s2[3]);
            c2 = fg * c2 + ig * gg;
            gstore2(&Pn[(size_t)j2 * Bb + fb], make_float2(h1v, og * tanhfast(c2)));
        }

        gbar(flags, wgid, tid, (u32)(t + 2));

        const float2* tp = Pc; Pc = Pn; Pn = (float2*)tp;
    }
    // final h2 = Pc[.].y

    // ---------- FC head: WG wgid handles batch wgid (reuse smem) ----------
    float* hh  = fcb;
    float* a1s = fcb + Hh;
    float* a2s = fcb + Hh + 256;
    hh[tid] = Pc[(size_t)tid * Bb + wgid].y;   // cached, fresh post-fence
    __syncthreads();
    if (tid < 256) {
        float acc = fc1_b[tid];
        const float* wr = fc1_W + (size_t)tid * Hh;
        for (int i = 0; i < Hh; ++i) acc += wr[i] * hh[i];
        a1s[tid] = fmaxf(acc, 0.0f);
    }
    __syncthreads();
    if (tid < 128) {
        float acc = fc2_b[tid];
        const float* wr = fc2_W + (size_t)tid * 256;
        for (int i = 0; i < 256; ++i) acc += wr[i] * a1s[i];
        a2s[tid] = fmaxf(acc, 0.0f);
    }
    __syncthreads();
    if (tid == 0) {
        float acc = fc3_b[0];
        for (int i = 0; i < 128; ++i) acc += fc3_W[i] * a2s[i];
        out[wgid] = acc;
    }
}

extern "C" void kernel_launch(void* const* d_in, const int* in_sizes, int n_in,
                              void* d_out, int out_size, void* d_ws, size_t ws_size,
                              hipStream_t stream)
{
    (void)in_sizes; (void)n_in; (void)out_size; (void)ws_size;

    const float* input = (const float*)d_in[0];
    const float* l1_Wx = (const float*)d_in[1];
    const float* l1_bx = (const float*)d_in[2];
    const float* l1_Wh = (const float*)d_in[3];
    const float* l1_bh = (const float*)d_in[4];
    const float* l2_Wx = (const float*)d_in[5];
    const float* l2_bx = (const float*)d_in[6];
    const float* l2_Wh = (const float*)d_in[7];
    const float* l2_bh = (const float*)d_in[8];
    const float* fc1_W = (const float*)d_in[9];
    const float* fc1_b = (const float*)d_in[10];
    const float* fc2_W = (const float*)d_in[11];
    const float* fc2_b = (const float*)d_in[12];
    const float* fc3_W = (const float*)d_in[13];
    const float* fc3_b = (const float*)d_in[14];
    float* out = (float*)d_out;
    float* ws  = (float*)d_ws;

    hipFuncSetAttribute((const void*)lstm_fused,
                        hipFuncAttributeMaxDynamicSharedMemorySize, SMEM_BYTES);

    void* args[] = {
        &input,
        &l1_Wx, &l1_bx, &l1_Wh, &l1_bh,
        &l2_Wx, &l2_bx, &l2_Wh, &l2_bh,
        &fc1_W, &fc1_b, &fc2_W, &fc2_b, &fc3_W, &fc3_b,
        &out, &ws
    };
    hipLaunchCooperativeKernel((void*)lstm_fused, dim3(NWG), dim3(NTHR), args,
                               SMEM_BYTES, stream);
}